// Round 13
// baseline (426.335 us; speedup 1.0000x reference)
//
#include <hip/hip_runtime.h>
#include <stdint.h>

#define B_ 8
#define T_ 4096
#define D_ 1024
#define H_ 1024
#define M_ (B_*T_)   /* 32768 */
#define K_ D_
#define N_ H_
#define TC 32
#define NC (T_/TC)   /* 128 */

typedef short short8 __attribute__((ext_vector_type(8)));
typedef float f32x4 __attribute__((ext_vector_type(4)));
typedef unsigned short ushort8v __attribute__((ext_vector_type(8)));

__device__ __forceinline__ float bf2f(unsigned short u) {
    union { unsigned int i; float f; } x; x.i = ((unsigned int)u) << 16; return x.f;
}
__device__ __forceinline__ unsigned short f2bf(float f) {
    union { float f; unsigned int i; } x; x.f = f;
    unsigned int u = x.i;
    unsigned int r = u + 0x7fffu + ((u >> 16) & 1u);
    return (unsigned short)(r >> 16);
}
__device__ __forceinline__ void gld_lds16(const unsigned short* g, unsigned short* l) {
    __builtin_amdgcn_global_load_lds(
        (const __attribute__((address_space(1))) void*)(const void*)g,
        (__attribute__((address_space(3))) void*)(void*)l, 16, 0, 0);
}
// sigmoid/gfun via raw v_rcp_f32 (1 instr) instead of IEEE divide chain.
__device__ __forceinline__ float sigm_neg(float k) {   // 1/(1+exp(k)) = 1 - sigmoid(k)
    return __builtin_amdgcn_rcpf(1.f + __expf(k));
}
__device__ __forceinline__ float gfun(float x) {       // x>=0: x+0.5 ; x<0: sigmoid(x)
    float neg = __builtin_amdgcn_rcpf(1.f + __expf(-x));
    return x >= 0.f ? x + 0.5f : neg;
}
// nontemporal helpers: builtin requires ext-vector types, not HIP_vector_type
__device__ __forceinline__ f32x4 nt_load_f4(const float* p) {
    return __builtin_nontemporal_load(reinterpret_cast<const f32x4*>(p));
}
__device__ __forceinline__ void nt_store_f4(float* p, float a, float b, float c, float d) {
    f32x4 v = {a, b, c, d};
    __builtin_nontemporal_store(v, reinterpret_cast<f32x4*>(p));
}

// ---------------- fp32 -> bf16 convert: x, Wz, Wh in ONE launch ----------------
// x is read-once: nontemporal loads keep it from polluting L3 (which must hold f/g
// later). xb store stays cached (gemm re-reads it).
__global__ void cvt_all(const float* __restrict__ x, const float* __restrict__ Wz,
                        const float* __restrict__ Wh,
                        unsigned short* __restrict__ xb, unsigned short* __restrict__ wzb,
                        unsigned short* __restrict__ whb) {
    const float* src;
    unsigned short* dst;
    int n4;
    if (blockIdx.y == 0)      { src = x;  dst = xb;  n4 = M_ * K_ / 4; }
    else if (blockIdx.y == 1) { src = Wz; dst = wzb; n4 = N_ * K_ / 4; }
    else                      { src = Wh; dst = whb; n4 = N_ * K_ / 4; }
    int i = blockIdx.x * blockDim.x + threadIdx.x;
    const int stride = gridDim.x * blockDim.x;
    for (; i < n4; i += stride) {
        f32x4 v = nt_load_f4(src + (size_t)i * 4);
        ushort4 o;
        o.x = f2bf(v.x); o.y = f2bf(v.y); o.z = f2bf(v.z); o.w = f2bf(v.w);
        ((ushort4*)dst)[i] = o;
    }
}

// ---------------- bf16 MFMA GEMM: 256x256 tile, 8-phase, persistent (steady state) -------
// PARKED at ~141 us / MfmaUtil 41%. The 128-AGPR accumulator leaves only 128 VGPRs at
// 8-wave residency (unified file, 256/wave), so the read-ahead pipeline cannot fit:
// R3 and R8 both spilled (WRITE_SIZE tripwire). Do not re-attempt without shrinking acc.
// R13 change: epilogue applies the ACTIVATION before storing (hidden in pipeline slack):
//   mat=0 -> stores f = 1 - sigmoid(k_z)  (bf16)
//   mat=1 -> stores g = gfun(k_h)         (bf16)
// so the scans become pure FMA streams (no exp/rcp). f/g also gain precision: computed
// from the unrounded f32 accumulator instead of bf16-rounded k.
#define SB() __builtin_amdgcn_sched_barrier(0)
#define BAR() do { SB(); __builtin_amdgcn_s_barrier(); SB(); } while (0)

__global__ __launch_bounds__(512, 2) void gemm_kernel(
    const unsigned short* __restrict__ Xb,
    const unsigned short* __restrict__ Wzb,
    const unsigned short* __restrict__ Whb,
    const float* __restrict__ bz, const float* __restrict__ bh,
    unsigned short* __restrict__ FOut, unsigned short* __restrict__ GOut)
{
    __shared__ __align__(16) unsigned short ldsA[2][256 * 64];
    __shared__ __align__(16) unsigned short ldsB[2][256 * 64];

    const int bx = blockIdx.x;      // row-supertile: rows [bx*1024, bx*1024+1024)
    const int bn = blockIdx.y;
    const int mat = blockIdx.z;
    const unsigned short* Wb = mat ? Whb : Wzb;
    const float* bias = mat ? bh : bz;
    unsigned short* Out = mat ? GOut : FOut;

    const int tid = threadIdx.x;
    const int w = tid >> 6, lane = tid & 63;
    const int wm = w >> 2, wn = w & 3;       // 2 x 4 wave grid; wave owns 128x64 of C

    // ---- staging addressing (inverse-swizzled global source) ----
    const int srow = lane >> 3;                       // row within 8-row wave group
    const int schunk = ((lane & 7) ^ srow) << 3;      // ushort offset of 16B chunk
    const unsigned short* gA = Xb + (size_t)(bx * 1024 + srow) * K_ + schunk;
    const unsigned short* gB = Wb + (size_t)(bn * 256 + srow) * K_ + schunk;

// global K-step g: A row-block = (g>>4)*256 within the supertile, kt = g&15
#define STAGE_A(s, g, h) do { \
    gld_lds16(gA + (size_t)(((g) >> 4) * 256 + (h)*128 + w*8) * K_ + ((g)&15) * 64, \
              &ldsA[s][((h)*128 + w*8) * 64]); \
    gld_lds16(gA + (size_t)(((g) >> 4) * 256 + (h)*128 + 64 + w*8) * K_ + ((g)&15) * 64, \
              &ldsA[s][((h)*128 + 64 + w*8) * 64]); \
  } while (0)
#define STAGE_B(s, g, h) do { \
    gld_lds16(gB + (size_t)((h)*128 + w*8) * K_ + ((g)&15) * 64, \
              &ldsB[s][((h)*128 + w*8) * 64]); \
    gld_lds16(gB + (size_t)((h)*128 + 64 + w*8) * K_ + ((g)&15) * 64, \
              &ldsB[s][((h)*128 + 64 + w*8) * 64]); \
  } while (0)

    // ---- fragment read addressing (swizzled) ----
    const int lrow = lane & 15;
    const int q = lane >> 4;
    const int sw0 = (q ^ (lane & 7)) << 3;   // ushort offset of kh=0 slot; kh=1 is ^32

#define LDA(s, fm, kh) (*(const short8*)&ldsA[s][(wm*128 + (fm)*16 + lrow) * 64 + (sw0 ^ ((kh)*32))])
#define LDB(s, fn, kh) (*(const short8*)&ldsB[s][(wn*64  + (fn)*16 + lrow) * 64 + (sw0 ^ ((kh)*32))])

#define RD_A4(s, fmb) do { \
    _Pragma("unroll") for (int f = 0; f < 4; ++f) { Ar[f][0] = LDA(s, (fmb)+f, 0); Ar[f][1] = LDA(s, (fmb)+f, 1); } \
  } while (0)
#define RD_B2(s, fnb) do { \
    _Pragma("unroll") for (int g2_ = 0; g2_ < 2; ++g2_) { Br[(fnb)+g2_][0] = LDB(s, (fnb)+g2_, 0); Br[(fnb)+g2_][1] = LDB(s, (fnb)+g2_, 1); } \
  } while (0)

#define QUAD(mb, nb) do { \
    __builtin_amdgcn_s_setprio(1); \
    _Pragma("unroll") for (int f = 0; f < 4; ++f) { \
      _Pragma("unroll") for (int g2_ = 0; g2_ < 2; ++g2_) { \
        acc[(mb)+f][(nb)+g2_] = __builtin_amdgcn_mfma_f32_16x16x32_bf16(Ar[f][0], Br[(nb)+g2_][0], acc[(mb)+f][(nb)+g2_], 0, 0, 0); \
        acc[(mb)+f][(nb)+g2_] = __builtin_amdgcn_mfma_f32_16x16x32_bf16(Ar[f][1], Br[(nb)+g2_][1], acc[(mb)+f][(nb)+g2_], 0, 0, 0); \
      } \
    } \
    __builtin_amdgcn_s_setprio(0); \
  } while (0)

    f32x4 acc[8][4];
    short8 Ar[4][2], Br[4][2];

    // bias values are t-invariant; hoist
    float bb[4];
#pragma unroll
    for (int fn = 0; fn < 4; ++fn) bb[fn] = bias[bn * 256 + wn * 64 + fn * 16 + lrow];

    // ---- prologue: g=0 (slot0, A+B all halves) + g=1 B halves ----
    STAGE_B(0, 0, 0); STAGE_B(0, 0, 1);
    STAGE_A(0, 0, 0); STAGE_A(0, 0, 1);
    STAGE_B(1, 1, 0); STAGE_B(1, 1, 1);
    SB();
    asm volatile("s_waitcnt vmcnt(4)" ::: "memory");   // g=0 landed; g=1 B in flight
    BAR();

#pragma unroll 1
    for (int t = 0; t < 4; ++t) {
#pragma unroll
        for (int i = 0; i < 8; ++i)
#pragma unroll
            for (int j = 0; j < 4; ++j) acc[i][j] = (f32x4){0.f, 0.f, 0.f, 0.f};

#pragma unroll 1
        for (int i = 0; i < 8; ++i) {
            const int g1 = t * 16 + 2 * i + 1;
            const int g2 = g1 + 1;
            const int g3 = g1 + 2;
            const bool st = (g2 < 64);   // false only at t=3,i=7

            // ---- P1: read slot0 A(m0-3)+B(n0-1); stage slot1 A-h0 (g1) ----
            RD_A4(0, 0); RD_B2(0, 0);
            STAGE_A(1, g1, 0);
            BAR();
            QUAD(0, 0);
            BAR();
            // ---- P2: read slot0 B(n2-3); stage slot1 A-h1 (g1) ----
            RD_B2(0, 2);
            STAGE_A(1, g1, 1);
            BAR();
            QUAD(0, 2);
            BAR();
            // ---- P3: read slot0 A(m4-7); stage slot0 B-h0 (g2) ----
            RD_A4(0, 4);
            if (st) STAGE_B(0, g2, 0);
            BAR();
            QUAD(4, 0);
            BAR();
            // ---- P4: stage slot0 B-h1 (g2); GATE: g1 landed before P5 ----
            if (st) {
                STAGE_B(0, g2, 1);
                SB();
                asm volatile("s_waitcnt vmcnt(4)" ::: "memory");
            } else {
                asm volatile("s_waitcnt vmcnt(0)" ::: "memory");   // final drain
            }
            BAR();
            QUAD(4, 2);
            BAR();
            // ---- P5: read slot1 A(m0-3)+B(n0-1); stage slot0 A-h0 (g2) ----
            RD_A4(1, 0); RD_B2(1, 0);
            if (st) STAGE_A(0, g2, 0);
            BAR();
            QUAD(0, 0);
            BAR();
            // ---- P6: read slot1 B(n2-3); stage slot0 A-h1 (g2) ----
            RD_B2(1, 2);
            if (st) STAGE_A(0, g2, 1);
            BAR();
            QUAD(0, 2);
            BAR();
            // ---- P7: read slot1 A(m4-7); stage slot1 B-h0 (g3) ----
            RD_A4(1, 4);
            if (st) STAGE_B(1, g3, 0);
            BAR();
            QUAD(4, 0);
            BAR();
            // ---- P8: stage slot1 B-h1 (g3); GATE: g2 (slot0) landed before next P1 ----
            if (st) {
                STAGE_B(1, g3, 1);
                SB();
                asm volatile("s_waitcnt vmcnt(4)" ::: "memory");
            }
            BAR();
            QUAD(4, 2);
            BAR();
        }

        // ---- per-tile epilogue (no LDS, runs under in-flight prefetch) ----
        // K[m][n] at ((m>>2)*N + n)*4 + (m&3); m = (bx*4+t)*256 + wm*128 + fm*16 + q*4 + r
        // Activation fused here (pipeline slack); f/g writes stay CACHED for the scans.
#pragma unroll
        for (int fn = 0; fn < 4; ++fn) {
            const int n = bn * 256 + wn * 64 + fn * 16 + lrow;
#pragma unroll
            for (int fm = 0; fm < 8; ++fm) {
                const int mq = (bx * 4 + t) * 64 + wm * 32 + fm * 4 + q;
                float v0 = acc[fm][fn][0] + bb[fn];
                float v1 = acc[fm][fn][1] + bb[fn];
                float v2 = acc[fm][fn][2] + bb[fn];
                float v3 = acc[fm][fn][3] + bb[fn];
                ushort4 o;
                if (mat == 0) {
                    o.x = f2bf(sigm_neg(v0));
                    o.y = f2bf(sigm_neg(v1));
                    o.z = f2bf(sigm_neg(v2));
                    o.w = f2bf(sigm_neg(v3));
                } else {
                    o.x = f2bf(gfun(v0));
                    o.y = f2bf(gfun(v1));
                    o.z = f2bf(gfun(v2));
                    o.w = f2bf(gfun(v3));
                }
                *(ushort4*)(Out + ((size_t)mq * N_ + n) * 4) = o;
            }
        }
    }
}

// Packed-layout accessor note for scans:
// F/G[m][n] lives at ((m>>2)*N + n)*4 + (m&3), m = b*T + t.
// A thread owning columns hb..hb+3 loads, per t-quad q, two 16B vectors:
//   base = ((b*1024 + (t0>>2))*N + hb)*4 ; v0 = cols hb,hb+1 ; v1 = cols hb+2,hb+3
//   value(col j, t0+r) = v[j>>1][(j&1)*4 + r]

// per-t-quad math, shared by scanA/scanC — PURE FMA now (activations pre-applied):
// f = Fb value; v = (1-f)*g
#define QUAD_MATH(Z0, Z1, HH0, HH1, CYSTMT)                                            \
    _Pragma("unroll")                                                                  \
    for (int r = 0; r < 4; r++) {                                                      \
        float ff[4] = {bf2f(Z0[r]), bf2f(Z0[4 + r]), bf2f(Z1[r]), bf2f(Z1[4 + r])};    \
        float gg[4] = {bf2f(HH0[r]), bf2f(HH0[4 + r]), bf2f(HH1[r]), bf2f(HH1[4 + r])};\
        _Pragma("unroll")                                                              \
        for (int j = 0; j < 4; j++) {                                                  \
            float f = ff[j];                                                           \
            float v = (1.f - f) * gg[j];                                               \
            CYSTMT                                                                     \
        }                                                                              \
    }

// ---------------- scan A: per-chunk affine aggregates (F = prod f, V) ----------------
// 2-deep register prefetch (best-measured variant, R5)
__global__ __launch_bounds__(256) void scanA_kernel(const unsigned short* __restrict__ Fb,
                                                    const unsigned short* __restrict__ Gb,
                                                    float* __restrict__ Fc, float* __restrict__ Vc)
{
    const int c = blockIdx.x, b = blockIdx.y;
    const int hb = threadIdx.x * 4;
    float F[4] = {1.f, 1.f, 1.f, 1.f}, V[4] = {0.f, 0.f, 0.f, 0.f};
    const size_t base0 = ((size_t)(b * (T_ / 4) + c * (TC / 4)) * N_ + hb) * 4;
    const size_t str = (size_t)N_ * 4;
    ushort8v cz0 = *(const ushort8v*)(Fb + base0);
    ushort8v cz1 = *(const ushort8v*)(Fb + base0 + 8);
    ushort8v ch0 = *(const ushort8v*)(Gb + base0);
    ushort8v ch1 = *(const ushort8v*)(Gb + base0 + 8);
    ushort8v az0 = *(const ushort8v*)(Fb + base0 + str);
    ushort8v az1 = *(const ushort8v*)(Fb + base0 + str + 8);
    ushort8v ah0 = *(const ushort8v*)(Gb + base0 + str);
    ushort8v ah1 = *(const ushort8v*)(Gb + base0 + str + 8);
#pragma unroll 1
    for (int qq = 0; qq < TC / 4; qq++) {
        const int qn = (qq + 2 < TC / 4) ? qq + 2 : TC / 4 - 1;   // clamped tail (L1-hot)
        const size_t nb = base0 + (size_t)qn * str;
        ushort8v bz0 = *(const ushort8v*)(Fb + nb);
        ushort8v bz1 = *(const ushort8v*)(Fb + nb + 8);
        ushort8v bh0 = *(const ushort8v*)(Gb + nb);
        ushort8v bh1 = *(const ushort8v*)(Gb + nb + 8);
        QUAD_MATH(cz0, cz1, ch0, ch1, { V[j] = f * V[j] + v; F[j] *= f; })
        cz0 = az0; cz1 = az1; ch0 = ah0; ch1 = ah1;
        az0 = bz0; az1 = bz1; ah0 = bh0; ah1 = bh1;
    }
    size_t o = ((size_t)(b * NC + c)) * H_ + hb;
    *(float4*)(Fc + o) = make_float4(F[0], F[1], F[2], F[3]);
    *(float4*)(Vc + o) = make_float4(V[0], V[1], V[2], V[3]);
}

// ---------------- scan C: self-carry + replay (scanB folded in) ----------------
// Out is write-once/never-read: NONTEMPORAL stores keep the 134 MB of Out from
// evicting the L3-resident f/g this kernel is still reading (R12: -25 us).
__global__ __launch_bounds__(256) void scanC_kernel(const unsigned short* __restrict__ Fb,
                                                    const unsigned short* __restrict__ Gb,
                                                    const float* __restrict__ Fc,
                                                    const float* __restrict__ Vc,
                                                    const float* __restrict__ h0,
                                                    float* __restrict__ Out)
{
    const int c = blockIdx.x, b = blockIdx.y;
    const int hb = threadIdx.x * 4;

    // ---- carry from h0 through chunks [0, c) ----
    float cy[4];
#pragma unroll
    for (int k = 0; k < 4; ++k) cy[k] = gfun(h0[(size_t)b * H_ + hb + k]);
    if (c == 0) {
        nt_store_f4(Out + (size_t)b * (T_ + 1) * H_ + hb, cy[0], cy[1], cy[2], cy[3]);
    }
    {
        size_t o = ((size_t)(b * NC)) * H_ + hb;
        int j = 0;
        while (j < c) {
            const int bnc = (c - j < 8) ? (c - j) : 8;
            float4 Fbv[8], Vbv[8];
#pragma unroll
            for (int k = 0; k < 8; ++k) {
                if (k < bnc) {
                    Fbv[k] = *(const float4*)(Fc + o + (size_t)k * H_);
                    Vbv[k] = *(const float4*)(Vc + o + (size_t)k * H_);
                }
            }
#pragma unroll
            for (int k = 0; k < 8; ++k) {
                if (k < bnc) {
                    cy[0] = Fbv[k].x * cy[0] + Vbv[k].x;
                    cy[1] = Fbv[k].y * cy[1] + Vbv[k].y;
                    cy[2] = Fbv[k].z * cy[2] + Vbv[k].z;
                    cy[3] = Fbv[k].w * cy[3] + Vbv[k].w;
                }
            }
            o += (size_t)bnc * H_;
            j += bnc;
        }
    }

    // ---- replay chunk with carry (2-deep prefetch, NT output stores) ----
    const size_t base0 = ((size_t)(b * (T_ / 4) + c * (TC / 4)) * N_ + hb) * 4;
    const size_t str = (size_t)N_ * 4;
    size_t ob = ((size_t)(b * (T_ + 1) + c * TC + 1)) * H_ + hb;
    ushort8v cz0 = *(const ushort8v*)(Fb + base0);
    ushort8v cz1 = *(const ushort8v*)(Fb + base0 + 8);
    ushort8v ch0 = *(const ushort8v*)(Gb + base0);
    ushort8v ch1 = *(const ushort8v*)(Gb + base0 + 8);
    ushort8v az0 = *(const ushort8v*)(Fb + base0 + str);
    ushort8v az1 = *(const ushort8v*)(Fb + base0 + str + 8);
    ushort8v ah0 = *(const ushort8v*)(Gb + base0 + str);
    ushort8v ah1 = *(const ushort8v*)(Gb + base0 + str + 8);
#pragma unroll 1
    for (int qq = 0; qq < TC / 4; qq++) {
        const int qn = (qq + 2 < TC / 4) ? qq + 2 : TC / 4 - 1;
        const size_t nb = base0 + (size_t)qn * str;
        ushort8v bz0 = *(const ushort8v*)(Fb + nb);
        ushort8v bz1 = *(const ushort8v*)(Fb + nb + 8);
        ushort8v bh0 = *(const ushort8v*)(Gb + nb);
        ushort8v bh1 = *(const ushort8v*)(Gb + nb + 8);
        QUAD_MATH(cz0, cz1, ch0, ch1, {
            cy[j] = f * cy[j] + v;
            if (j == 3) {
                nt_store_f4(Out + ob, cy[0], cy[1], cy[2], cy[3]);
                ob += H_;
            }
        })
        cz0 = az0; cz1 = az1; ch0 = ah0; ch1 = ah1;
        az0 = bz0; az1 = bz1; ah0 = bh0; ah1 = bh1;
    }
}

extern "C" void kernel_launch(void* const* d_in, const int* in_sizes, int n_in,
                              void* d_out, int out_size, void* d_ws, size_t ws_size,
                              hipStream_t stream)
{
    const float* x  = (const float*)d_in[0];
    const float* h0 = (const float*)d_in[1];
    const float* Wz = (const float*)d_in[2];
    const float* bz = (const float*)d_in[3];
    const float* Wh = (const float*)d_in[4];
    const float* bh = (const float*)d_in[5];
    float* out = (float*)d_out;

    char* ws = (char*)d_ws;
    unsigned short* xb  = (unsigned short*)ws; ws += (size_t)M_ * K_ * 2;   // 64 MiB
    unsigned short* wzb = (unsigned short*)ws; ws += (size_t)N_ * K_ * 2;   // 2 MiB
    unsigned short* whb = (unsigned short*)ws; ws += (size_t)N_ * K_ * 2;   // 2 MiB
    unsigned short* fb  = (unsigned short*)ws; ws += (size_t)M_ * N_ * 2;   // 64 MiB
    unsigned short* gb  = (unsigned short*)ws; ws += (size_t)M_ * N_ * 2;   // 64 MiB
    float* Fc    = (float*)ws; ws += (size_t)B_ * NC * H_ * 4;              // 4 MiB
    float* Vc    = (float*)ws; ws += (size_t)B_ * NC * H_ * 4;              // 4 MiB

    cvt_all<<<dim3(2048, 3), 256, 0, stream>>>(x, Wz, Wh, xb, wzb, whb);

    dim3 gg(M_ / 1024, N_ / 256, 2);
    gemm_kernel<<<gg, 512, 0, stream>>>(xb, wzb, whb, bz, bh, fb, gb);

    scanA_kernel<<<dim3(NC, B_), 256, 0, stream>>>(fb, gb, Fc, Vc);
    scanC_kernel<<<dim3(NC, B_), 256, 0, stream>>>(fb, gb, Fc, Vc, h0, out);
}